// Round 1
// baseline (61.984 us; speedup 1.0000x reference)
//
#include <hip/hip_runtime.h>

#define HOP 160
#define FFT 1024
#define PAD (FFT / 2)
#define NUM_LABELS 72
#define BATCH 4
#define T 240000
#define NOUT 1501   // (T + 2*PAD - FFT)/HOP + 1

// One block per (window, batch). 256 threads.
// Per-wave LDS sub-histograms (4 waves) to cut ds-atomic contention,
// then merge + argmax with lowest-index tiebreak (jnp.argmax semantics).
__global__ __launch_bounds__(256) void label_window_argmax(
    const int* __restrict__ lbl, int* __restrict__ out)
{
    __shared__ int hist[4][NUM_LABELS];
    __shared__ int keys[NUM_LABELS];

    const int tid  = threadIdx.x;
    const int wave = tid >> 6;

    // zero sub-histograms
    for (int i = tid; i < 4 * NUM_LABELS; i += 256)
        ((int*)hist)[i] = 0;
    __syncthreads();

    const int w = blockIdx.x;      // window index [0, 1501)
    const int b = blockIdx.y;      // batch       [0, 4)
    const int* __restrict__ row = lbl + b * T;
    const int start = w * HOP - PAD;   // position in unpadded coords

    // 1024 window elements, 4 per thread, coalesced (reflection segments
    // at the edges are contiguous-reversed — still one memory segment).
#pragma unroll
    for (int k = 0; k < FFT / 256; ++k) {
        int j = start + tid + k * 256;
        j = (j < 0) ? -j : j;                    // left reflect  (no edge repeat)
        j = (j >= T) ? (2 * (T - 1) - j) : j;    // right reflect
        const int lab = row[j];
        atomicAdd(&hist[wave][lab], 1);
    }
    __syncthreads();

    // merge 4 sub-histograms; pack (count, inverted label) so a max-reduce
    // picks the highest count and, on ties, the LOWEST label index.
    if (tid < NUM_LABELS) {
        const int tot = hist[0][tid] + hist[1][tid] + hist[2][tid] + hist[3][tid];
        keys[tid] = (tot << 7) | (NUM_LABELS - 1 - tid);   // tot <= 1024, fits easily
    }
    __syncthreads();

    if (tid == 0) {
        int best = keys[0];
#pragma unroll
        for (int i = 1; i < NUM_LABELS; ++i)
            best = max(best, keys[i]);
        out[b * NOUT + w] = NUM_LABELS - 1 - (best & 127);
    }
}

extern "C" void kernel_launch(void* const* d_in, const int* in_sizes, int n_in,
                              void* d_out, int out_size, void* d_ws, size_t ws_size,
                              hipStream_t stream) {
    const int* lbl = (const int*)d_in[0];
    // d_in[1] is the frozen all-ones conv weight: conv == windowed count, ignore.
    int* out = (int*)d_out;

    dim3 grid(NOUT, BATCH);
    label_window_argmax<<<grid, 256, 0, stream>>>(lbl, out);
}

// Round 2
// 61.230 us; speedup vs baseline: 1.0123x; 1.0123x over previous
//
#include <hip/hip_runtime.h>

#define HOP 160
#define FFT 1024
#define PAD (FFT / 2)
#define NUM_LABELS 72
#define BATCH 4
#define T 240000
#define NOUT 1501              // (T + 2*PAD - FFT)/HOP + 1
#define R 8                    // windows per block (sliding)
#define NBLK ((NOUT + R - 1) / R)   // 188

// One block per (R windows, batch row). Sliding histogram: window w+1 =
// window w - 160 old elements + 160 new elements. Per-wave LDS sub-hists
// cut ds-atomic same-address serialization; argmax via 64-lane shuffle
// butterfly on packed keys (count<<7 | inverted label) so max-reduce
// matches jnp.argmax lowest-index tiebreak.
__global__ __launch_bounds__(256) void label_window_argmax(
    const int* __restrict__ lbl, int* __restrict__ out)
{
    __shared__ int hist[4][NUM_LABELS];
    __shared__ int keys[NUM_LABELS];

    const int tid  = threadIdx.x;
    const int wave = tid >> 6;
    const int lane = tid & 63;

    for (int i = tid; i < 4 * NUM_LABELS; i += 256)
        ((int*)hist)[i] = 0;

    const int b  = blockIdx.y;
    const int w0 = blockIdx.x * R;
    const int* __restrict__ row = lbl + b * T;

    auto refl = [&](int j) {
        j = (j < 0) ? -j : j;                   // left reflect (no edge repeat)
        j = (j >= T) ? (2 * (T - 1) - j) : j;   // right reflect
        return j;
    };

    __syncthreads();

    // build full histogram for window w0: 1024 elements, 4 per thread
    {
        const int s = w0 * HOP - PAD;
#pragma unroll
        for (int k = 0; k < 4; ++k) {
            const int lab = row[refl(s + tid + k * 256)];
            atomicAdd(&hist[wave][lab], 1);
        }
    }

    for (int step = 0; step < R; ++step) {
        const int w = w0 + step;
        if (w >= NOUT) break;                   // block-uniform
        __syncthreads();                        // updates done before merge

        if (tid < NUM_LABELS) {
            const int tot = hist[0][tid] + hist[1][tid] + hist[2][tid] + hist[3][tid];
            keys[tid] = (tot << 7) | (NUM_LABELS - 1 - tid);
        }
        __syncthreads();                        // keys ready

        if (wave == 0) {
            int k = keys[lane];                              // lanes 0..63
            if (lane < NUM_LABELS - 64)                      // fold 64..71
                k = max(k, keys[64 + lane]);
#pragma unroll
            for (int off = 32; off; off >>= 1)
                k = max(k, __shfl_xor(k, off, 64));
            if (lane == 0)
                out[b * NOUT + w] = NUM_LABELS - 1 - (k & 127);
        }

        // slide to window w+1: -[s, s+160), +[s+1024, s+1184)
        if (step + 1 < R && w + 1 < NOUT) {
            const int s = w * HOP - PAD;
            if (tid < HOP) {
                const int lab = row[refl(s + tid)];
                atomicAdd(&hist[wave][lab], -1);
            }
            const int t2 = tid - (256 - HOP);   // tid in [96,256) -> [0,160)
            if (t2 >= 0) {
                const int lab = row[refl(s + FFT + t2)];
                atomicAdd(&hist[wave][lab], 1);
            }
        }
        // top-of-loop __syncthreads orders: wave0's keys-read precedes it,
        // next merge's keys-write follows it — no extra barrier needed.
    }
}

extern "C" void kernel_launch(void* const* d_in, const int* in_sizes, int n_in,
                              void* d_out, int out_size, void* d_ws, size_t ws_size,
                              hipStream_t stream) {
    const int* lbl = (const int*)d_in[0];
    // d_in[1] is the frozen all-ones conv weight: conv == windowed count, ignore.
    int* out = (int*)d_out;

    dim3 grid(NBLK, BATCH);
    label_window_argmax<<<grid, 256, 0, stream>>>(lbl, out);
}